// Round 12
// baseline (364.947 us; speedup 1.0000x reference)
//
#include <hip/hip_runtime.h>

#define SS 512
#define DD 768
#define TT 64

// max(a, dpp<CTRL>(b)) -- CTRL compile-time; DPP runs on the VALU pipe.
template <int CTRL>
__device__ __forceinline__ float dppmax(float a, float b) {
    int bi = __float_as_int(b);
    int pi = __builtin_amdgcn_update_dpp(bi, bi, CTRL, 0xF, 0xF, false);
    return fmaxf(a, __int_as_float(pi));
}
#define DPP_QUAD_XOR1 0xB1   // quad_perm [1,0,3,2] = lane^1
#define DPP_QUAD_XOR2 0x4E   // quad_perm [2,3,0,1] = lane^2
#define DPP_ROW_HALF_MIRROR 0x141  // lane^7 within 8
#define DPP_ROW_MIRROR      0x140  // lane^15 within 16

// ---------------------------------------------------------------------------
// Kernel 1: emissions GEMM  em[b*512+s][t] = sum_d x[b,s,d]*W[t,d] + bias[t]
// 128x64 tile, grid 256, 256 threads, thread tile 8x4 (R1-validated).
// ---------------------------------------------------------------------------
__global__ __launch_bounds__(256) void emis_gemm(
    const float* __restrict__ X, const float* __restrict__ W,
    const float* __restrict__ bias, float* __restrict__ em)
{
    __shared__ __align__(16) float Xs[16][132];
    __shared__ __align__(16) float Ws[16][68];

    const int tid = threadIdx.x;
    const int m0  = blockIdx.x * 128;
    const int tm  = tid >> 4;
    const int tn  = tid & 15;
    const int lm  = tid >> 2;
    const int lkq = tid & 3;
    const int wt  = tid & 63;
    const int wkq = tid >> 6;

    float acc[8][4];
#pragma unroll
    for (int i = 0; i < 8; i++)
#pragma unroll
        for (int j = 0; j < 4; j++) acc[i][j] = 0.f;

    float4 xr0, xr1, wr;
    xr0 = *(const float4*)&X[(size_t)(m0 + lm) * DD + lkq * 4];
    xr1 = *(const float4*)&X[(size_t)(m0 + lm + 64) * DD + lkq * 4];
    wr  = *(const float4*)&W[(size_t)wt * DD + wkq * 4];

    for (int t = 0; t < 48; t++) {
        Xs[lkq * 4 + 0][lm] = xr0.x;  Xs[lkq * 4 + 1][lm] = xr0.y;
        Xs[lkq * 4 + 2][lm] = xr0.z;  Xs[lkq * 4 + 3][lm] = xr0.w;
        Xs[lkq * 4 + 0][lm + 64] = xr1.x;  Xs[lkq * 4 + 1][lm + 64] = xr1.y;
        Xs[lkq * 4 + 2][lm + 64] = xr1.z;  Xs[lkq * 4 + 3][lm + 64] = xr1.w;
        Ws[wkq * 4 + 0][wt] = wr.x;  Ws[wkq * 4 + 1][wt] = wr.y;
        Ws[wkq * 4 + 2][wt] = wr.z;  Ws[wkq * 4 + 3][wt] = wr.w;
        __syncthreads();

        if (t < 47) {
            const int k0 = (t + 1) * 16;
            xr0 = *(const float4*)&X[(size_t)(m0 + lm) * DD + k0 + lkq * 4];
            xr1 = *(const float4*)&X[(size_t)(m0 + lm + 64) * DD + k0 + lkq * 4];
            wr  = *(const float4*)&W[(size_t)wt * DD + k0 + wkq * 4];
        }

#pragma unroll
        for (int k = 0; k < 16; k++) {
            float a[8], bv[4];
            *(float4*)&a[0] = *(const float4*)&Xs[k][tm * 8];
            *(float4*)&a[4] = *(const float4*)&Xs[k][tm * 8 + 4];
            *(float4*)&bv[0] = *(const float4*)&Ws[k][tn * 4];
#pragma unroll
            for (int i = 0; i < 8; i++)
#pragma unroll
                for (int j = 0; j < 4; j++)
                    acc[i][j] = fmaf(a[i], bv[j], acc[i][j]);
        }
        __syncthreads();
    }

    const float4 bv4 = *(const float4*)&bias[tn * 4];
#pragma unroll
    for (int i = 0; i < 8; i++) {
        const size_t row = (size_t)(m0 + tm * 8 + i);
        float4 o;
        o.x = acc[i][0] + bv4.x;  o.y = acc[i][1] + bv4.y;
        o.z = acc[i][2] + bv4.z;  o.w = acc[i][3] + bv4.w;
        *(float4*)&em[row * TT + tn * 4] = o;
    }
}

// ---------------------------------------------------------------------------
// Kernel 2: Viterbi forward, VALUE ONLY, DPP butterfly reduce-scatter.
// One wave per batch (64 x 64), waves_per_eu(1,1) (R10: unlocks VGPR budget).
// Lane p owns score[p]; slot j holds cand(f=p^j) = score[p] + trans[p][p^j].
// Stage mask m merges lane p's slot j with lane p^m's slot j^m (same f):
//   v[j] = max(v[j], lanexor_m(v[j^m]))
// Masks 15,7,2,1 are DPP (ROW_MIRROR / ROW_HALF_MIRROR / quad_perm) = VALU
// speed; only masks 16,32 use shfl (3 DS ops/step). After all stages lane p
// slot 0 = max_p' cand(p); sc = that + em (bit-exact vs reference: cand
// rounded once as (score+trans), max exact, +em rounds once -- R5/R10
// validated this exact value recursion end-to-end).
// ---------------------------------------------------------------------------
__global__ __launch_bounds__(64)
__attribute__((amdgpu_waves_per_eu(1, 1)))
void viterbi_fwd(
    const float* __restrict__ em, const float* __restrict__ trans,
    float* __restrict__ scoreHist, int* __restrict__ bestTag)
{
    __shared__ __align__(16) float tr_lds[64 * 68];  // padded rows (bank spread)

    const int b    = blockIdx.x;
    const int lane = threadIdx.x;
    const float* emb = em + (size_t)b * SS * TT;
    float* sh = scoreHist + (size_t)b * SS * TT;

    // stage trans into padded LDS (row r at tr_lds[r*68], 16B-aligned)
    {
        const float4* src = (const float4*)trans;
#pragma unroll
        for (int i = 0; i < 16; i++) {
            const int q = i * 64 + lane;        // float4 index 0..1023
            const int r = q >> 4, c = q & 15;
            *(float4*)&tr_lds[r * 68 + c * 4] = src[q];
        }
    }
    __syncthreads();

    // tpk[j] = trans[lane][lane^j]  (pre-permuted row, VGPR-resident)
    float tpk[TT];
#pragma unroll
    for (int j = 0; j < TT; j++) tpk[j] = tr_lds[lane * 68 + (lane ^ j)];

    float sc = emb[lane];   // score_0[lane]
    sh[lane] = sc;

    float er0 = emb[1 * TT + lane];
    float er1 = emb[2 * TT + lane];
    float er2 = emb[3 * TT + lane];
    float er3 = emb[4 * TT + lane];

    auto step = [&](int s, float em_v) {
        float v[TT];
#pragma unroll
        for (int j = 0; j < TT; j++) v[j] = sc + tpk[j];

        // stage m=15 (ROW_MIRROR): keep j with bit3==0 (32 ops)
#pragma unroll
        for (int j = 0; j < TT; j++)
            if ((j & 8) == 0) v[j] = dppmax<DPP_ROW_MIRROR>(v[j], v[j ^ 15]);
        // stage m=7 (ROW_HALF_MIRROR): keep j&12==0 (16 ops)
#pragma unroll
        for (int j = 0; j < TT; j++)
            if ((j & 12) == 0) v[j] = dppmax<DPP_ROW_HALF_MIRROR>(v[j], v[j ^ 7]);
        // stage m=2 (quad xor2): keep j&14==0 (8 ops)
#pragma unroll
        for (int j = 0; j < TT; j++)
            if ((j & 14) == 0) v[j] = dppmax<DPP_QUAD_XOR2>(v[j], v[j ^ 2]);
        // stage m=1 (quad xor1): keep j&15==0 (4 ops)
#pragma unroll
        for (int j = 0; j < TT; j++)
            if ((j & 15) == 0) v[j] = dppmax<DPP_QUAD_XOR1>(v[j], v[j ^ 1]);
        // stage m=16 (shfl): slots {0,16} and {32,48}
        v[0]  = fmaxf(v[0],  __shfl_xor(v[16], 16, 64));
        v[32] = fmaxf(v[32], __shfl_xor(v[48], 16, 64));
        // stage m=32 (shfl): slots {0,32}
        sc = fmaxf(v[0], __shfl_xor(v[32], 32, 64)) + em_v;

        sh[s * TT + lane] = sc;   // history for bp_kernel (fire-and-forget)
    };

    for (int sb = 1; sb <= 505; sb += 4) {
        step(sb + 0, er0);  er0 = emb[(sb + 4) * TT + lane];
        step(sb + 1, er1);  er1 = emb[(sb + 5) * TT + lane];
        step(sb + 2, er2);  er2 = emb[(sb + 6) * TT + lane];
        step(sb + 3, er3);  er3 = emb[((sb + 7) <= 511 ? (sb + 7) : 511) * TT + lane];
    }
    step(509, er0);
    step(510, er1);
    step(511, er2);

    // final argmax across lanes (first-index ties)
    float fv = sc;
    int   fa = lane;
#pragma unroll
    for (int m = 1; m <= 32; m <<= 1) {
        const float vo = __shfl_xor(fv, m, 64);
        const int   ao = __shfl_xor(fa, m, 64);
        if (vo > fv || (vo == fv && ao < fa)) { fv = vo; fa = ao; }
    }
    if (lane == 0) bestTag[b] = fa;
}

// ---------------------------------------------------------------------------
// Kernel 3: backpointer recompute, massively parallel. One wave per (b,s),
// lane = cur. v[p] = (score_{s-1}[p] + trans[p][cur]) + em_s[cur] with
// exact reference rounding; left-wins tournament == first-index argmax.
// ---------------------------------------------------------------------------
__global__ __launch_bounds__(256) void bp_kernel(
    const float* __restrict__ scoreHist, const float* __restrict__ em,
    const float* __restrict__ trans, unsigned char* __restrict__ hist8)
{
    __shared__ __align__(16) float tr_lds[4096];  // 16 KB: trans[64][64]
    const int tid = threadIdx.x;
    {
        const float4* src = (const float4*)trans;
        float4* dst = (float4*)tr_lds;
        for (int i = tid; i < 1024; i += 256) dst[i] = src[i];
    }
    __syncthreads();

    const int wv   = tid >> 6;
    const int lane = tid & 63;
    const int g    = blockIdx.x * 4 + wv;   // 0..32703
    const int b    = g / 511;
    const int s    = 1 + (g % 511);

    const float4* sb4 = (const float4*)(scoreHist + ((size_t)b * SS + (s - 1)) * TT);
    const float em_v = em[((size_t)b * SS + s) * TT + lane];

    float treg[TT];
#pragma unroll
    for (int p = 0; p < TT; p++) treg[p] = tr_lds[p * TT + lane];

    float4 sq[16];
#pragma unroll
    for (int i = 0; i < 16; i++) sq[i] = sb4[i];

    float v[TT];
#pragma unroll
    for (int i = 0; i < 16; i++) {
        v[4 * i + 0] = (sq[i].x + treg[4 * i + 0]) + em_v;
        v[4 * i + 1] = (sq[i].y + treg[4 * i + 1]) + em_v;
        v[4 * i + 2] = (sq[i].z + treg[4 * i + 2]) + em_v;
        v[4 * i + 3] = (sq[i].w + treg[4 * i + 3]) + em_v;
    }
    // left-wins tournament (== numpy first-index argmax)
    float m1[32]; int a1[32];
#pragma unroll
    for (int i = 0; i < 32; i++) {
        const bool t = v[2 * i + 1] > v[2 * i];
        m1[i] = t ? v[2 * i + 1] : v[2 * i];
        a1[i] = 2 * i + (t ? 1 : 0);
    }
    float m2[16]; int a2[16];
#pragma unroll
    for (int i = 0; i < 16; i++) {
        const bool t = m1[2 * i + 1] > m1[2 * i];
        m2[i] = t ? m1[2 * i + 1] : m1[2 * i];
        a2[i] = t ? a1[2 * i + 1] : a1[2 * i];
    }
    float m3[8]; int a3[8];
#pragma unroll
    for (int i = 0; i < 8; i++) {
        const bool t = m2[2 * i + 1] > m2[2 * i];
        m3[i] = t ? m2[2 * i + 1] : m2[2 * i];
        a3[i] = t ? a2[2 * i + 1] : a2[2 * i];
    }
    float m4[4]; int a4[4];
#pragma unroll
    for (int i = 0; i < 4; i++) {
        const bool t = m3[2 * i + 1] > m3[2 * i];
        m4[i] = t ? m3[2 * i + 1] : m3[2 * i];
        a4[i] = t ? a3[2 * i + 1] : a3[2 * i];
    }
    float m5[2]; int a5[2];
#pragma unroll
    for (int i = 0; i < 2; i++) {
        const bool t = m4[2 * i + 1] > m4[2 * i];
        m5[i] = t ? m4[2 * i + 1] : m4[2 * i];
        a5[i] = t ? a4[2 * i + 1] : a4[2 * i];
    }
    const bool t6 = m5[1] > m5[0];
    const int barg = t6 ? a5[1] : a5[0];

    hist8[((size_t)b * SS + s) * TT + lane] = (unsigned char)barg;
}

// ---------------------------------------------------------------------------
// Kernel 4: backtrack via LDS path doubling, 1024 threads, 4-wide batched
// dependent loads. hist8 layout: [b][s][t], rows s=1..511 valid.
// ---------------------------------------------------------------------------
__global__ __launch_bounds__(1024) void backtrack(
    const unsigned char* __restrict__ hist8, const int* __restrict__ bestTag,
    int* __restrict__ out)
{
    __shared__ unsigned char A[511 * 64];
    __shared__ unsigned char Bf[511 * 64];

    const int b   = blockIdx.x;
    const int tid = threadIdx.x;
    const unsigned char* h8 = hist8 + (size_t)b * SS * TT;

    for (int idx = tid; idx < 511 * 64; idx += 1024) A[idx] = h8[idx + 64];
    __syncthreads();

    unsigned char* curT = A;
    unsigned char* nxtT = Bf;
    for (int d = 1; d < 511; d <<= 1) {
        for (int gQ = 0; gQ < 7; gQ++) {
            int i0 = tid + (gQ * 4 + 0) * 1024;
            int i1 = tid + (gQ * 4 + 1) * 1024;
            int i2 = tid + (gQ * 4 + 2) * 1024;
            int i3 = tid + (gQ * 4 + 3) * 1024;
            int s0 = i0 >> 6, s1 = i1 >> 6, s2 = i2 >> 6, s3 = i3 >> 6;
            int a0 = (s0 + d >= 511) ? i0 : (s0 + d) * 64 + (i0 & 63);
            int a1 = (s1 + d >= 511) ? i1 : (s1 + d) * 64 + (i1 & 63);
            int a2 = (s2 + d >= 511) ? i2 : (s2 + d) * 64 + (i2 & 63);
            int a3 = (s3 + d >= 511) ? i3 : (s3 + d) * 64 + (i3 & 63);
            unsigned char q0 = curT[a0], q1 = curT[a1], q2 = curT[a2], q3 = curT[a3];
            int f0 = (s0 + d >= 511) ? i0 : s0 * 64 + q0;
            int f1 = (s1 + d >= 511) ? i1 : s1 * 64 + q1;
            int f2 = (s2 + d >= 511) ? i2 : s2 * 64 + q2;
            int f3 = (s3 + d >= 511) ? i3 : s3 * 64 + q3;
            nxtT[i0] = curT[f0];  nxtT[i1] = curT[f1];
            nxtT[i2] = curT[f2];  nxtT[i3] = curT[f3];
        }
        for (int j = 28; j < 31; j++) {
            int i0 = tid + j * 1024;
            int s0 = i0 >> 6;
            int a0 = (s0 + d >= 511) ? i0 : (s0 + d) * 64 + (i0 & 63);
            unsigned char q0 = curT[a0];
            int f0 = (s0 + d >= 511) ? i0 : s0 * 64 + q0;
            nxtT[i0] = curT[f0];
        }
        {
            int i0 = tid + 31 * 1024;
            if (i0 < 511 * 64) {
                int s0 = i0 >> 6;
                int a0 = (s0 + d >= 511) ? i0 : (s0 + d) * 64 + (i0 & 63);
                unsigned char q0 = curT[a0];
                int f0 = (s0 + d >= 511) ? i0 : s0 * 64 + q0;
                nxtT[i0] = curT[f0];
            }
        }
        __syncthreads();
        unsigned char* tmp = curT; curT = nxtT; nxtT = tmp;
    }

    const int bt = bestTag[b];
    for (int s = tid; s < SS; s += 1024) {
        const int tag = (s == 511) ? bt : (int)curT[s * 64 + bt];
        out[(size_t)b * SS + s] = tag;
    }
}

// ---------------------------------------------------------------------------
extern "C" void kernel_launch(void* const* d_in, const int* in_sizes, int n_in,
                              void* d_out, int out_size, void* d_ws, size_t ws_size,
                              hipStream_t stream)
{
    const float* X     = (const float*)d_in[0];  // [64,512,768]
    const float* W     = (const float*)d_in[1];  // [64,768]
    const float* bias  = (const float*)d_in[2];  // [64]
    const float* trans = (const float*)d_in[3];  // [64,64]
    int* out = (int*)d_out;                      // [64,512] int32

    char* ws = (char*)d_ws;
    float*         em        = (float*)ws;                      // 8,388,608 B
    float*         scoreHist = (float*)(ws + 8388608);          // 8,388,608 B
    unsigned char* hist8     = (unsigned char*)(ws + 16777216); // 2,097,152 B
    int*           bestTag   = (int*)(ws + 18874368);           // 256 B

    emis_gemm<<<dim3(256), dim3(256), 0, stream>>>(X, W, bias, em);
    viterbi_fwd<<<dim3(64), dim3(64), 0, stream>>>(em, trans, scoreHist, bestTag);
    bp_kernel<<<dim3(8176), dim3(256), 0, stream>>>(scoreHist, em, trans, hist8);
    backtrack<<<dim3(64), dim3(1024), 0, stream>>>(hist8, bestTag, out);
}

// Round 13
// 227.420 us; speedup vs baseline: 1.6047x; 1.6047x over previous
//
#include <hip/hip_runtime.h>

#define SS 512
#define DD 768
#define TT 64

typedef __attribute__((ext_vector_type(2))) float f32x2;

__device__ __forceinline__ f32x2 vmax2(f32x2 a, f32x2 b) {
    return __builtin_elementwise_max(a, b);
}

// ---------------------------------------------------------------------------
// Kernel 1: emissions GEMM  em[b*512+s][t] = sum_d x[b,s,d]*W[t,d] + bias[t]
// 64x64 tile, grid 512 (2 blocks/CU), 256 threads, thread tile 4x4. (R10)
// ---------------------------------------------------------------------------
__global__ __launch_bounds__(256) void emis_gemm(
    const float* __restrict__ X, const float* __restrict__ W,
    const float* __restrict__ bias, float* __restrict__ em)
{
    __shared__ __align__(16) float Xs[16][68];
    __shared__ __align__(16) float Ws[16][68];

    const int tid = threadIdx.x;
    const int m0  = blockIdx.x * 64;
    const int tm  = tid >> 4;
    const int tn  = tid & 15;
    const int lr  = tid >> 2;
    const int lk  = tid & 3;

    float acc[4][4];
#pragma unroll
    for (int i = 0; i < 4; i++)
#pragma unroll
        for (int j = 0; j < 4; j++) acc[i][j] = 0.f;

    float4 xr, wr;
    xr = *(const float4*)&X[(size_t)(m0 + lr) * DD + lk * 4];
    wr = *(const float4*)&W[(size_t)lr * DD + lk * 4];

    for (int t = 0; t < 48; t++) {
        Xs[lk * 4 + 0][lr] = xr.x;  Xs[lk * 4 + 1][lr] = xr.y;
        Xs[lk * 4 + 2][lr] = xr.z;  Xs[lk * 4 + 3][lr] = xr.w;
        Ws[lk * 4 + 0][lr] = wr.x;  Ws[lk * 4 + 1][lr] = wr.y;
        Ws[lk * 4 + 2][lr] = wr.z;  Ws[lk * 4 + 3][lr] = wr.w;
        __syncthreads();

        if (t < 47) {
            const int k0 = (t + 1) * 16;
            xr = *(const float4*)&X[(size_t)(m0 + lr) * DD + k0 + lk * 4];
            wr = *(const float4*)&W[(size_t)lr * DD + k0 + lk * 4];
        }

#pragma unroll
        for (int k = 0; k < 16; k++) {
            float a[4], bv[4];
            *(float4*)&a[0]  = *(const float4*)&Xs[k][tm * 4];
            *(float4*)&bv[0] = *(const float4*)&Ws[k][tn * 4];
#pragma unroll
            for (int i = 0; i < 4; i++)
#pragma unroll
                for (int j = 0; j < 4; j++)
                    acc[i][j] = fmaf(a[i], bv[j], acc[i][j]);
        }
        __syncthreads();
    }

    const float4 bv4 = *(const float4*)&bias[tn * 4];
#pragma unroll
    for (int i = 0; i < 4; i++) {
        const size_t row = (size_t)(m0 + tm * 4 + i);
        float4 o;
        o.x = acc[i][0] + bv4.x;  o.y = acc[i][1] + bv4.y;
        o.z = acc[i][2] + bv4.z;  o.w = acc[i][3] + bv4.w;
        *(float4*)&em[row * TT + tn * 4] = o;
    }
}

// ---------------------------------------------------------------------------
// Kernel 2: Viterbi forward, VALUE ONLY (exact R10 code, 112 us measured).
// One wave per batch, waves_per_eu(1,1) keeps tpk[32] VGPR-resident.
// Step: 16 broadcast ds_read_b128 -> 32 pk_add -> 31 pk_max tree -> fmax
// -> +em -> ds_write. Bit-exact vs reference (monotone rounding).
// ---------------------------------------------------------------------------
__global__ __launch_bounds__(64)
__attribute__((amdgpu_waves_per_eu(1, 1)))
void viterbi_fwd(
    const float* __restrict__ em, const float* __restrict__ trans,
    float* __restrict__ scoreHist, int* __restrict__ bestTag)
{
    __shared__ __align__(16) float sc_lds[TT];
    __shared__ __align__(16) float tr_lds[4096];

    const int b    = blockIdx.x;
    const int lane = threadIdx.x;
    const float* emb = em + (size_t)b * SS * TT;
    float* sh = scoreHist + (size_t)b * SS * TT;

    {
        float4* dst = (float4*)tr_lds;
        const float4* src = (const float4*)trans;
#pragma unroll
        for (int i = 0; i < 16; i++) dst[lane + i * 64] = src[lane + i * 64];
    }
    __syncthreads();

    // tpk[j] = (trans[2j][lane], trans[2j+1][lane])
    f32x2 tpk[32];
#pragma unroll
    for (int j = 0; j < 32; j++) {
        tpk[j].x = tr_lds[(2 * j) * TT + lane];
        tpk[j].y = tr_lds[(2 * j + 1) * TT + lane];
    }

    const float em0 = emb[lane];
    sc_lds[lane] = em0;
    sh[lane] = em0;   // score_0
    float sc = em0;

    float er0 = emb[1 * TT + lane];
    float er1 = emb[2 * TT + lane];
    float er2 = emb[3 * TT + lane];
    float er3 = emb[4 * TT + lane];

    float4 sq[16];
    {
        const float4* sb = (const float4*)sc_lds;
#pragma unroll
        for (int i = 0; i < 16; i++) sq[i] = sb[i];
    }

    auto step = [&](int s, float em_v) {
        const f32x2* sq2 = (const f32x2*)sq;
        f32x2 pk[32];
#pragma unroll
        for (int j = 0; j < 32; j++) pk[j] = sq2[j] + tpk[j];

#pragma unroll
        for (int m = 16; m >= 1; m >>= 1)
#pragma unroll
            for (int j = 0; j < 16; j++) {
                if (j < m) pk[j] = vmax2(pk[j], pk[j + m]);
            }
        sc = fmaxf(pk[0].x, pk[0].y) + em_v;

        sc_lds[lane] = sc;
        {
            const float4* sb = (const float4*)sc_lds;
#pragma unroll
            for (int i = 0; i < 16; i++) sq[i] = sb[i];
        }
        sh[s * TT + lane] = sc;
    };

    for (int sb = 1; sb <= 505; sb += 4) {
        step(sb + 0, er0);  er0 = emb[(sb + 4) * TT + lane];
        step(sb + 1, er1);  er1 = emb[(sb + 5) * TT + lane];
        step(sb + 2, er2);  er2 = emb[(sb + 6) * TT + lane];
        step(sb + 3, er3);  er3 = emb[((sb + 7) <= 511 ? (sb + 7) : 511) * TT + lane];
    }
    step(509, er0);
    step(510, er1);
    step(511, er2);

    float fv = sc;
    int   fa = lane;
#pragma unroll
    for (int m = 1; m <= 32; m <<= 1) {
        const float vo = __shfl_xor(fv, m, 64);
        const int   ao = __shfl_xor(fa, m, 64);
        if (vo > fv || (vo == fv && ao < fa)) { fv = vo; fa = ao; }
    }
    if (lane == 0) bestTag[b] = fa;
}

// ---------------------------------------------------------------------------
// Kernel 3: backpointer recompute, massively parallel. One wave per (b,s),
// lane = cur. The max value is already known bit-exact: sh = scoreHist[s][cur]
// (monotone rounding: max_i fl(cand_i+em) == fl(max cand + em) == sh).
// So no tournament: compute v[i] = fl(fl(score+trans)+em) (packed) and take
// the FIRST index with v[i]==sh  == numpy first-index argmax.
// ---------------------------------------------------------------------------
__global__ __launch_bounds__(256) void bp_kernel(
    const float* __restrict__ scoreHist, const float* __restrict__ em,
    const float* __restrict__ trans, unsigned char* __restrict__ hist8)
{
    __shared__ __align__(16) float tr_lds[4096];  // trans[64][64]
    const int tid = threadIdx.x;
    {
        const float4* src = (const float4*)trans;
        float4* dst = (float4*)tr_lds;
        for (int i = tid; i < 1024; i += 256) dst[i] = src[i];
    }
    __syncthreads();

    const int wv   = tid >> 6;
    const int lane = tid & 63;
    const int g    = blockIdx.x * 4 + wv;   // 0..32703
    const int b    = g / 511;
    const int s    = 1 + (g % 511);

    const f32x2* sb2 = (const f32x2*)(scoreHist + ((size_t)b * SS + (s - 1)) * TT);
    const float em_v = em[((size_t)b * SS + s) * TT + lane];
    const float sh_v = scoreHist[((size_t)b * SS + s) * TT + lane];

    // tpk[j] = (trans[2j][lane], trans[2j+1][lane])
    f32x2 tpk[32];
#pragma unroll
    for (int j = 0; j < 32; j++) {
        tpk[j].x = tr_lds[(2 * j) * TT + lane];
        tpk[j].y = tr_lds[(2 * j + 1) * TT + lane];
    }

    f32x2 em2; em2.x = em_v; em2.y = em_v;
    f32x2 v2[32];
#pragma unroll
    for (int j = 0; j < 32; j++) {
        f32x2 cand = sb2[j] + tpk[j];   // fl(score+trans), packed
        v2[j] = cand + em2;             // fl(cand+em), packed
    }

    // first index i with v[i] == sh_v (descending scan, .y before .x)
    int idx = 63;
#pragma unroll
    for (int j = 31; j >= 0; j--) {
        idx = (v2[j].y == sh_v) ? 2 * j + 1 : idx;
        idx = (v2[j].x == sh_v) ? 2 * j     : idx;
    }

    hist8[((size_t)b * SS + s) * TT + lane] = (unsigned char)idx;
}

// ---------------------------------------------------------------------------
// Kernel 4: backtrack via readlane pointer-chase. One wave per batch.
// tag is wave-uniform -> tag_{s-1} = v_readlane(row_s, tag) (~10 cy/step);
// rows prefetched 4 ahead into registers. Replaces LDS path doubling
// (~35 us of dependent ds_read_u8 issue) with ~3 us.
// ---------------------------------------------------------------------------
__global__ __launch_bounds__(64) void backtrack(
    const unsigned char* __restrict__ hist8, const int* __restrict__ bestTag,
    int* __restrict__ out)
{
    __shared__ int tags[SS];

    const int b    = blockIdx.x;
    const int lane = threadIdx.x;
    const unsigned char* h8 = hist8 + (size_t)b * SS * TT;

    int tag = bestTag[b];                 // uniform
    if (lane == 0) tags[511] = tag;

    // prefetch rows 511,510,509,508 (lane l holds hist8[s][l])
    int r0 = h8[511 * TT + lane];
    int r1 = h8[510 * TT + lane];
    int r2 = h8[509 * TT + lane];
    int r3 = h8[508 * TT + lane];

    // steps s = 511 .. 8 (126 iterations x 4)
    for (int sb = 511; sb >= 11; sb -= 4) {
        tag = __builtin_amdgcn_readlane(r0, tag);
        if (lane == 0) tags[sb - 1] = tag;
        r0 = h8[(sb - 4) * TT + lane];
        tag = __builtin_amdgcn_readlane(r1, tag);
        if (lane == 0) tags[sb - 2] = tag;
        r1 = h8[(sb - 5) * TT + lane];
        tag = __builtin_amdgcn_readlane(r2, tag);
        if (lane == 0) tags[sb - 3] = tag;
        r2 = h8[(sb - 6) * TT + lane];
        tag = __builtin_amdgcn_readlane(r3, tag);
        if (lane == 0) tags[sb - 4] = tag;
        r3 = h8[(sb - 7) * TT + lane];
    }
    // after loop: r0..r3 = rows 7,6,5,4 ; steps s = 7..4
    tag = __builtin_amdgcn_readlane(r0, tag);  if (lane == 0) tags[6] = tag;
    tag = __builtin_amdgcn_readlane(r1, tag);  if (lane == 0) tags[5] = tag;
    tag = __builtin_amdgcn_readlane(r2, tag);  if (lane == 0) tags[4] = tag;
    tag = __builtin_amdgcn_readlane(r3, tag);  if (lane == 0) tags[3] = tag;
    // steps s = 3,2,1
    int q0 = h8[3 * TT + lane];
    int q1 = h8[2 * TT + lane];
    int q2 = h8[1 * TT + lane];
    tag = __builtin_amdgcn_readlane(q0, tag);  if (lane == 0) tags[2] = tag;
    tag = __builtin_amdgcn_readlane(q1, tag);  if (lane == 0) tags[1] = tag;
    tag = __builtin_amdgcn_readlane(q2, tag);  if (lane == 0) tags[0] = tag;

    __syncthreads();
#pragma unroll
    for (int s = 0; s < 8; s++)
        out[(size_t)b * SS + s * 64 + lane] = tags[s * 64 + lane];
}

// ---------------------------------------------------------------------------
extern "C" void kernel_launch(void* const* d_in, const int* in_sizes, int n_in,
                              void* d_out, int out_size, void* d_ws, size_t ws_size,
                              hipStream_t stream)
{
    const float* X     = (const float*)d_in[0];  // [64,512,768]
    const float* W     = (const float*)d_in[1];  // [64,768]
    const float* bias  = (const float*)d_in[2];  // [64]
    const float* trans = (const float*)d_in[3];  // [64,64]
    int* out = (int*)d_out;                      // [64,512] int32

    char* ws = (char*)d_ws;
    float*         em        = (float*)ws;                      // 8,388,608 B
    float*         scoreHist = (float*)(ws + 8388608);          // 8,388,608 B
    unsigned char* hist8     = (unsigned char*)(ws + 16777216); // 2,097,152 B
    int*           bestTag   = (int*)(ws + 18874368);           // 256 B

    emis_gemm<<<dim3(512), dim3(256), 0, stream>>>(X, W, bias, em);
    viterbi_fwd<<<dim3(64), dim3(64), 0, stream>>>(em, trans, scoreHist, bestTag);
    bp_kernel<<<dim3(8176), dim3(256), 0, stream>>>(scoreHist, em, trans, hist8);
    backtrack<<<dim3(64), dim3(64), 0, stream>>>(hist8, bestTag, out);
}